// Round 2
// baseline (79.761 us; speedup 1.0000x reference)
//
#include <hip/hip_runtime.h>
#include <hip/hip_bf16.h>

#define MARGIN 1.0f
#define C_DIM 1024

// ---------------------------------------------------------------------------
// Kernel 1: one block per row, fully fused.
//   Phase 0: detect mask storage width (bool-as-uint8 vs int32 vs fp16/bf16
//            vs fp32) by scanning the first in_sizes[1] BYTES of the mask
//            buffer (minimum possible size — always in bounds). Redundant
//            per block; the buffer is L2-resident, cost ~0.5 us aggregate.
//   Phase 1: stage row scores (float4) + positive flags in LDS; compact the
//            positive scores via a shared-atomic append.
//   Phase 2: each thread strides over negatives with an inner loop over the
//            ~10 positives; wave shuffle-reduce; tid0 stores per-row partials
//            (plain stores — no init, no global atomics needed):
//              partial[row]     = sum relu(s_n - s_p + margin)
//              partial[B + row] = n_pos * (C - n_pos)
// ---------------------------------------------------------------------------
__global__ __launch_bounds__(256) void row_loss_fused(
    const float* __restrict__ scores, const void* __restrict__ mask,
    int mask_elems, float* __restrict__ partial) {
    __shared__ float s[C_DIM];
    __shared__ float ps[C_DIM];          // compacted positive scores
    __shared__ unsigned char pf[C_DIM];  // is-positive flag
    __shared__ int npos_sh;
    __shared__ unsigned int ev_sh;
    __shared__ float wsum[4];

    const int row = blockIdx.x;
    const int tid = threadIdx.x;
    if (tid == 0) { npos_sh = 0; ev_sh = 0u; }
    __syncthreads();

    // ---- Phase 0: mask dtype evidence ------------------------------------
    // bit0: byte==1 at byte-offset>0   -> 1-byte (numpy bool)
    // bit1: halfword==0x3F80/0x3C00    -> bf16/fp16 "1.0"
    // bit2: word==0x3F800000           -> fp32 1.0
    // none: int32 {0,1}                -> 4-byte nonzero test
    {
        const int nwords = mask_elems / 4;  // bytes lower-bound / 4
        const int nvec = nwords / 4;
        const uint4* wv = (const uint4*)mask;
        unsigned int ev = 0u;
        for (int i = tid; i < nvec; i += 256) {
            uint4 q = wv[i];
            unsigned int xs[4] = {q.x, q.y, q.z, q.w};
#pragma unroll
            for (int c = 0; c < 4; ++c) {
                unsigned int x = xs[c];
                if (x == 0u) continue;
                if (x == 0x3F800000u) ev |= 4u;
                unsigned int h0 = x & 0xFFFFu, h1 = x >> 16;
                if (h0 == 0x3F80u || h1 == 0x3F80u || h0 == 0x3C00u ||
                    h1 == 0x3C00u)
                    ev |= 2u;
                if (((x >> 8) & 0xFFu) == 1u || ((x >> 16) & 0xFFu) == 1u ||
                    ((x >> 24) & 0xFFu) == 1u)
                    ev |= 1u;
            }
        }
        // scalar tail (nwords not divisible by 4)
        for (int i = nvec * 4 + tid; i < nwords; i += 256) {
            unsigned int x = ((const unsigned int*)mask)[i];
            if (x == 0u) continue;
            if (x == 0x3F800000u) ev |= 4u;
            unsigned int h0 = x & 0xFFFFu, h1 = x >> 16;
            if (h0 == 0x3F80u || h1 == 0x3F80u || h0 == 0x3C00u ||
                h1 == 0x3C00u)
                ev |= 2u;
            if (((x >> 8) & 0xFFu) == 1u || ((x >> 16) & 0xFFu) == 1u ||
                ((x >> 24) & 0xFFu) == 1u)
                ev |= 1u;
        }
        if (ev) atomicOr(&ev_sh, ev);
    }
    __syncthreads();
    const unsigned int f = ev_sh;
    const int width = (f & 4u) ? 4 : (f & 2u) ? 2 : (f & 1u) ? 1 : 4;

    // ---- Phase 1: stage row ----------------------------------------------
    const long base = (long)row * C_DIM;
    ((float4*)s)[tid] = ((const float4*)(scores + base))[tid];

    for (int i = tid; i < C_DIM; i += 256) {
        bool p;
        if (width == 4)      p = ((const unsigned int*)mask)[base + i] != 0u;
        else if (width == 2) p = ((const unsigned short*)mask)[base + i] != 0;
        else                 p = ((const unsigned char*)mask)[base + i] != 0;
        pf[i] = p ? 1 : 0;
    }
    __syncthreads();

    for (int i = tid; i < C_DIM; i += 256) {
        if (pf[i]) {
            int k = atomicAdd(&npos_sh, 1);
            ps[k] = s[i];
        }
    }
    __syncthreads();

    // ---- Phase 2: pairwise hinge -----------------------------------------
    const int np = npos_sh;
    float local = 0.0f;
    for (int i = tid; i < C_DIM; i += 256) {
        if (!pf[i]) {
            const float sn = s[i] + MARGIN;
            for (int j = 0; j < np; ++j) local += fmaxf(sn - ps[j], 0.0f);
        }
    }

    for (int off = 32; off > 0; off >>= 1) local += __shfl_down(local, off);
    if ((tid & 63) == 0) wsum[tid >> 6] = local;
    __syncthreads();
    if (tid == 0) {
        partial[row] = wsum[0] + wsum[1] + wsum[2] + wsum[3];
        partial[gridDim.x + row] = (float)np * (float)(C_DIM - np);
    }
}

// ---------------------------------------------------------------------------
// Kernel 2: reduce per-row partials and finalize the scalar.
// ---------------------------------------------------------------------------
__global__ __launch_bounds__(256) void finalize_reduce(
    const float* __restrict__ partial, int B, float* __restrict__ out) {
    __shared__ float wl[4], wd[4];
    float l = 0.0f, d = 0.0f;
    for (int i = threadIdx.x; i < B; i += 256) {
        l += partial[i];
        d += partial[B + i];
    }
    for (int off = 32; off > 0; off >>= 1) {
        l += __shfl_down(l, off);
        d += __shfl_down(d, off);
    }
    const int lane = threadIdx.x & 63, wave = threadIdx.x >> 6;
    if (lane == 0) { wl[wave] = l; wd[wave] = d; }
    __syncthreads();
    if (threadIdx.x == 0) {
        const float L = wl[0] + wl[1] + wl[2] + wl[3];
        const float D = wd[0] + wd[1] + wd[2] + wd[3];
        out[0] = (D == 0.0f) ? 0.0f : L / D;
    }
}

extern "C" void kernel_launch(void* const* d_in, const int* in_sizes, int n_in,
                              void* d_out, int out_size, void* d_ws,
                              size_t ws_size, hipStream_t stream) {
    const float* scores = (const float*)d_in[0];
    const void* mask = d_in[1];

    const int B = in_sizes[0] / C_DIM;  // 128 for the reference shape
    float* partial = (float*)d_ws;      // [0,B): loss, [B,2B): denom

    row_loss_fused<<<B, 256, 0, stream>>>(scores, mask, in_sizes[1], partial);
    finalize_reduce<<<1, 256, 0, stream>>>(partial, B, (float*)d_out);
}

// Round 3
// 63.934 us; speedup vs baseline: 1.2476x; 1.2476x over previous
//
#include <hip/hip_runtime.h>
#include <hip/hip_bf16.h>

#define MARGIN 1.0f
#define C_DIM 1024

// ---------------------------------------------------------------------------
// Kernel 1: one block per row, fully fused.
//   Phase 0: detect mask storage width by scanning a 16 KB PREFIX of the
//            mask buffer (4096 words = 4 uint4/thread). 16 KB <= minimum
//            possible buffer size (in_sizes[1] elements >= 128 KB at width 1)
//            so always in bounds. Prefix covers >= 4096 elements even at
//            width 4 (~40 positives at p=0.01) -> detection deterministic.
//            L2-resident after first toucher; ~1 us exposed latency.
//            [R2 post-mortem: scanning the full 128 KB per block at
//             1 wave/SIMD occupancy exposed ~12 us of cold-miss latency.]
//   Phase 1: stage row scores (float4) + positive flags in LDS; compact
//            positive scores via shared-atomic append.
//   Phase 2: each thread strides over negatives, inner loop over the ~10
//            positives; wave shuffle-reduce; tid0 plain-stores per-row
//            partials (no init, no global atomics):
//              partial[row]     = sum relu(s_n - s_p + margin)
//              partial[B + row] = n_pos * (C - n_pos)
// ---------------------------------------------------------------------------
__global__ __launch_bounds__(256) void row_loss_fused(
    const float* __restrict__ scores, const void* __restrict__ mask,
    int mask_elems, float* __restrict__ partial) {
    __shared__ float s[C_DIM];
    __shared__ float ps[C_DIM];          // compacted positive scores
    __shared__ unsigned char pf[C_DIM];  // is-positive flag
    __shared__ int npos_sh;
    __shared__ unsigned int ev_sh;
    __shared__ float wsum[4];

    const int row = blockIdx.x;
    const int tid = threadIdx.x;
    if (tid == 0) { npos_sh = 0; ev_sh = 0u; }
    __syncthreads();

    // ---- Phase 0: mask dtype evidence (16 KB prefix) ---------------------
    // bit0: byte==1 at byte-offset>0   -> 1-byte (numpy bool)
    // bit1: halfword==0x3F80/0x3C00    -> bf16/fp16 "1.0"
    // bit2: word==0x3F800000           -> fp32 1.0
    // none: int32 {0,1}                -> 4-byte nonzero test
    {
        int nwords = mask_elems / 4;  // elements >= bytes/4: safe lower bound
        if (nwords > 4096) nwords = 4096;
        const int nvec = nwords / 4;  // uint4 count (4096/4 = 1024 = 4/thread)
        const uint4* wv = (const uint4*)mask;
        unsigned int ev = 0u;
#pragma unroll 4
        for (int i = tid; i < nvec; i += 256) {
            uint4 q = wv[i];
            unsigned int xs[4] = {q.x, q.y, q.z, q.w};
#pragma unroll
            for (int c = 0; c < 4; ++c) {
                unsigned int x = xs[c];
                if (x == 0u) continue;
                if (x == 0x3F800000u) ev |= 4u;
                unsigned int h0 = x & 0xFFFFu, h1 = x >> 16;
                if (h0 == 0x3F80u || h1 == 0x3F80u || h0 == 0x3C00u ||
                    h1 == 0x3C00u)
                    ev |= 2u;
                if (((x >> 8) & 0xFFu) == 1u || ((x >> 16) & 0xFFu) == 1u ||
                    ((x >> 24) & 0xFFu) == 1u)
                    ev |= 1u;
            }
        }
        if (ev) atomicOr(&ev_sh, ev);
    }
    __syncthreads();
    const unsigned int f = ev_sh;
    const int width = (f & 4u) ? 4 : (f & 2u) ? 2 : (f & 1u) ? 1 : 4;

    // ---- Phase 1: stage row ----------------------------------------------
    const long base = (long)row * C_DIM;
    ((float4*)s)[tid] = ((const float4*)(scores + base))[tid];

    for (int i = tid; i < C_DIM; i += 256) {
        bool p;
        if (width == 4)      p = ((const unsigned int*)mask)[base + i] != 0u;
        else if (width == 2) p = ((const unsigned short*)mask)[base + i] != 0;
        else                 p = ((const unsigned char*)mask)[base + i] != 0;
        pf[i] = p ? 1 : 0;
    }
    __syncthreads();

    for (int i = tid; i < C_DIM; i += 256) {
        if (pf[i]) {
            int k = atomicAdd(&npos_sh, 1);
            ps[k] = s[i];
        }
    }
    __syncthreads();

    // ---- Phase 2: pairwise hinge -----------------------------------------
    const int np = npos_sh;
    float local = 0.0f;
    for (int i = tid; i < C_DIM; i += 256) {
        if (!pf[i]) {
            const float sn = s[i] + MARGIN;
            for (int j = 0; j < np; ++j) local += fmaxf(sn - ps[j], 0.0f);
        }
    }

    for (int off = 32; off > 0; off >>= 1) local += __shfl_down(local, off);
    if ((tid & 63) == 0) wsum[tid >> 6] = local;
    __syncthreads();
    if (tid == 0) {
        partial[row] = wsum[0] + wsum[1] + wsum[2] + wsum[3];
        partial[gridDim.x + row] = (float)np * (float)(C_DIM - np);
    }
}

// ---------------------------------------------------------------------------
// Kernel 2: reduce per-row partials and finalize the scalar.
// ---------------------------------------------------------------------------
__global__ __launch_bounds__(256) void finalize_reduce(
    const float* __restrict__ partial, int B, float* __restrict__ out) {
    __shared__ float wl[4], wd[4];
    float l = 0.0f, d = 0.0f;
    for (int i = threadIdx.x; i < B; i += 256) {
        l += partial[i];
        d += partial[B + i];
    }
    for (int off = 32; off > 0; off >>= 1) {
        l += __shfl_down(l, off);
        d += __shfl_down(d, off);
    }
    const int lane = threadIdx.x & 63, wave = threadIdx.x >> 6;
    if (lane == 0) { wl[wave] = l; wd[wave] = d; }
    __syncthreads();
    if (threadIdx.x == 0) {
        const float L = wl[0] + wl[1] + wl[2] + wl[3];
        const float D = wd[0] + wd[1] + wd[2] + wd[3];
        out[0] = (D == 0.0f) ? 0.0f : L / D;
    }
}

extern "C" void kernel_launch(void* const* d_in, const int* in_sizes, int n_in,
                              void* d_out, int out_size, void* d_ws,
                              size_t ws_size, hipStream_t stream) {
    const float* scores = (const float*)d_in[0];
    const void* mask = d_in[1];

    const int B = in_sizes[0] / C_DIM;  // 128 for the reference shape
    float* partial = (float*)d_ws;      // [0,B): loss, [B,2B): denom

    row_loss_fused<<<B, 256, 0, stream>>>(scores, mask, in_sizes[1], partial);
    finalize_reduce<<<1, 256, 0, stream>>>(partial, B, (float*)d_out);
}

// Round 4
// 61.601 us; speedup vs baseline: 1.2948x; 1.0379x over previous
//
#include <hip/hip_runtime.h>
#include <hip/hip_bf16.h>

#define MARGIN 1.0f
#define C_DIM 1024

// ---------------------------------------------------------------------------
// Kernel 1: one block per row (256 threads, thread t owns elements 4t..4t+3).
//
// Latency plan (R3 post-mortem: 1 wave/SIMD occupancy -> no TLP, so the
// kernel's cost IS its serial memory-latency chain; overlap everything):
//   - issue score float4 load            (registers, independent)
//   - issue width-1 speculative mask word (bytes [row*1024, +1024) -- within
//     the first in_sizes[1] bytes for every row at ANY true width -> safe)
//   - issue 16 KB prefix-scan loads for mask dtype detection
//   then one sync, decode width, and in the expected uint8 case no further
//   global loads are needed. Wider layouts (int32 / f16 / f32) fall back to
//   a dependent load that is in-bounds exactly when detection selects them.
//
// Detection evidence (prefix = first 4096 words, always in bounds since
// elements >= bytes at width>=1):
//   bit0: byte==1 at byte-offset>0   -> 1-byte (numpy bool)
//   bit1: halfword==0x3F80/0x3C00    -> bf16/fp16 "1.0"
//   bit2: word==0x3F800000           -> fp32 1.0
//   none -> int32 {0,1} (word 0x00000001 sets no bits by construction)
//
// Output (plain stores, no init needed):
//   partial[row]     = sum_{n in neg, p in pos} relu(s_n - s_p + margin)
//   partial[B + row] = n_pos * (C - n_pos)
// ---------------------------------------------------------------------------
__global__ __launch_bounds__(256) void row_loss_fused(
    const float* __restrict__ scores, const void* __restrict__ mask,
    int mask_elems, float* __restrict__ partial) {
    __shared__ float ps[C_DIM];  // compacted positive scores (worst case C)
    __shared__ int npos_sh;
    __shared__ unsigned int ev_sh;
    __shared__ float wsum[4];

    const int row = blockIdx.x;
    const int tid = threadIdx.x;

    // ---- issue ALL independent global loads up front ---------------------
    const float4 sc = ((const float4*)scores)[row * 256 + tid];
    const unsigned int mw1 =
        ((const unsigned int*)mask)[row * 256 + tid];  // width-1 speculation

    int nwords = mask_elems / 4;  // elements >= bytes/4: safe lower bound
    if (nwords > 4096) nwords = 4096;
    const int nvec = nwords / 4;  // uint4 count (<= 1024 -> <= 4 per thread)
    uint4 q[4];
    int nq = 0;
#pragma unroll 4
    for (int i = tid; i < nvec; i += 256) q[nq++] = ((const uint4*)mask)[i];

    if (tid == 0) { npos_sh = 0; ev_sh = 0u; }
    __syncthreads();

    // ---- dtype evidence from the prefix ----------------------------------
    {
        unsigned int ev = 0u;
        for (int k = 0; k < nq; ++k) {
            unsigned int xs[4] = {q[k].x, q[k].y, q[k].z, q[k].w};
#pragma unroll
            for (int c = 0; c < 4; ++c) {
                unsigned int x = xs[c];
                if (x == 0u) continue;
                if (x == 0x3F800000u) ev |= 4u;
                unsigned int h0 = x & 0xFFFFu, h1 = x >> 16;
                if (h0 == 0x3F80u || h1 == 0x3F80u || h0 == 0x3C00u ||
                    h1 == 0x3C00u)
                    ev |= 2u;
                if (((x >> 8) & 0xFFu) == 1u || ((x >> 16) & 0xFFu) == 1u ||
                    ((x >> 24) & 0xFFu) == 1u)
                    ev |= 1u;
            }
        }
        if (ev) atomicOr(&ev_sh, ev);
    }
    __syncthreads();
    const unsigned int f = ev_sh;

    // ---- per-thread positive flags for elements 4t..4t+3 -----------------
    bool fl[4];
    if (f & 1u) {  // uint8 (expected): use the speculative preload
        fl[0] = (mw1 & 0xFFu) != 0u;
        fl[1] = ((mw1 >> 8) & 0xFFu) != 0u;
        fl[2] = ((mw1 >> 16) & 0xFFu) != 0u;
        fl[3] = ((mw1 >> 24) & 0xFFu) != 0u;
    } else if (f & 2u) {  // 2-byte: in-bounds iff detection correct
        uint2 h = ((const uint2*)mask)[row * 256 + tid];
        fl[0] = (h.x & 0xFFFFu) != 0u;
        fl[1] = (h.x >> 16) != 0u;
        fl[2] = (h.y & 0xFFFFu) != 0u;
        fl[3] = (h.y >> 16) != 0u;
    } else {  // 4-byte (int32 {0,1} or fp32): in-bounds iff detection correct
        uint4 w = ((const uint4*)mask)[row * 256 + tid];
        fl[0] = w.x != 0u; fl[1] = w.y != 0u;
        fl[2] = w.z != 0u; fl[3] = w.w != 0u;
    }

    // ---- compact positive scores into LDS --------------------------------
    const float sv[4] = {sc.x, sc.y, sc.z, sc.w};
#pragma unroll
    for (int c = 0; c < 4; ++c) {
        if (fl[c]) {
            int k = atomicAdd(&npos_sh, 1);
            ps[k] = sv[c];
        }
    }
    __syncthreads();

    // ---- pairwise hinge over own negatives -------------------------------
    const int np = npos_sh;
    float local = 0.0f;
#pragma unroll
    for (int c = 0; c < 4; ++c) {
        if (!fl[c]) {
            const float sn = sv[c] + MARGIN;
            for (int j = 0; j < np; ++j) local += fmaxf(sn - ps[j], 0.0f);
        }
    }

    for (int off = 32; off > 0; off >>= 1) local += __shfl_down(local, off);
    if ((tid & 63) == 0) wsum[tid >> 6] = local;
    __syncthreads();
    if (tid == 0) {
        partial[row] = wsum[0] + wsum[1] + wsum[2] + wsum[3];
        partial[gridDim.x + row] = (float)np * (float)(C_DIM - np);
    }
}

// ---------------------------------------------------------------------------
// Kernel 2: reduce per-row partials and finalize the scalar.
// ---------------------------------------------------------------------------
__global__ __launch_bounds__(256) void finalize_reduce(
    const float* __restrict__ partial, int B, float* __restrict__ out) {
    __shared__ float wl[4], wd[4];
    float l = 0.0f, d = 0.0f;
    for (int i = threadIdx.x; i < B; i += 256) {
        l += partial[i];
        d += partial[B + i];
    }
    for (int off = 32; off > 0; off >>= 1) {
        l += __shfl_down(l, off);
        d += __shfl_down(d, off);
    }
    const int lane = threadIdx.x & 63, wave = threadIdx.x >> 6;
    if (lane == 0) { wl[wave] = l; wd[wave] = d; }
    __syncthreads();
    if (threadIdx.x == 0) {
        const float L = wl[0] + wl[1] + wl[2] + wl[3];
        const float D = wd[0] + wd[1] + wd[2] + wd[3];
        out[0] = (D == 0.0f) ? 0.0f : L / D;
    }
}

extern "C" void kernel_launch(void* const* d_in, const int* in_sizes, int n_in,
                              void* d_out, int out_size, void* d_ws,
                              size_t ws_size, hipStream_t stream) {
    const float* scores = (const float*)d_in[0];
    const void* mask = d_in[1];

    const int B = in_sizes[0] / C_DIM;  // 128 for the reference shape
    float* partial = (float*)d_ws;      // [0,B): loss, [B,2B): denom

    row_loss_fused<<<B, 256, 0, stream>>>(scores, mask, in_sizes[1], partial);
    finalize_reduce<<<1, 256, 0, stream>>>(partial, B, (float*)d_out);
}